// Round 1
// baseline (721.489 us; speedup 1.0000x reference)
//
#include <hip/hip_runtime.h>
#include <math.h>

#define DIN  128
#define HC   128
#define CCH  64
#define NEG  0.2f

// ---------------------------------------------------------------------------
// CSR build
// ---------------------------------------------------------------------------
__global__ void hist_kernel(const int* __restrict__ ei, int E, int N,
                            int* __restrict__ counts) {
    int i = blockIdx.x * blockDim.x + threadIdx.x;
    int Etot = E + N;
    if (i >= Etot) return;
    int dst = (i < E) ? ei[E + i] : (i - E);
    if (dst < 0 || dst >= N) return;   // defensive (dtype mismatch insurance)
    atomicAdd(&counts[dst], 1);
}

__global__ void scan_kernel(const int* __restrict__ counts,
                            int* __restrict__ rowptr,
                            int* __restrict__ cursor, int n) {
    __shared__ int wsum[16];
    int tid  = threadIdx.x;          // 1024 threads
    int lane = tid & 63, wid = tid >> 6;
    int running = 0;
    for (int base = 0; base < n; base += 1024) {
        int i = base + tid;
        int v = (i < n) ? counts[i] : 0;
        int x = v;
        #pragma unroll
        for (int off = 1; off < 64; off <<= 1) {
            int y = __shfl_up(x, off, 64);
            if (lane >= off) x += y;
        }
        if (lane == 63) wsum[wid] = x;
        __syncthreads();
        if (tid < 16) {
            int w = wsum[tid];
            #pragma unroll
            for (int off = 1; off < 16; off <<= 1) {
                int y = __shfl_up(w, off, 64);
                if (tid >= off) w += y;
            }
            wsum[tid] = w;
        }
        __syncthreads();
        int excl = running + (wid ? wsum[wid - 1] : 0) + (x - v);
        if (i < n) { rowptr[i] = excl; cursor[i] = excl; }
        running += wsum[15];
        __syncthreads();
    }
    if (tid == 0) rowptr[n] = running;
}

__global__ void scatter_kernel(const int* __restrict__ ei, int E, int N,
                               int* __restrict__ cursor,
                               int* __restrict__ esrc) {
    int i = blockIdx.x * blockDim.x + threadIdx.x;
    int Etot = E + N;
    if (i >= Etot) return;
    int src = (i < E) ? ei[i]     : (i - E);
    int dst = (i < E) ? ei[E + i] : (i - E);
    if (dst < 0 || dst >= N || src < 0 || src >= N) return;
    int pos = atomicAdd(&cursor[dst], 1);
    esrc[pos] = src;
}

// ---------------------------------------------------------------------------
// Dual GEMM: xl = X@Wl + bl, xr = X@Wr + br.  X:[n,128], W:[128,128] row-major
// Block: 256 threads, 64-row tile, per-thread 8 rows x 4 cols for each of l/r.
// ---------------------------------------------------------------------------
__global__ __launch_bounds__(256) void gemm_dual(
        const float* __restrict__ X,
        const float* __restrict__ Wl, const float* __restrict__ bl,
        const float* __restrict__ Wr, const float* __restrict__ br,
        float* __restrict__ xl, float* __restrict__ xr, int nrows) {
    __shared__ float xs[64][128];
    int tid = threadIdx.x;
    int i0  = blockIdx.x * 64;

    #pragma unroll
    for (int it = 0; it < 8; ++it) {
        int f   = it * 256 + tid;          // float4 index within 64x128 tile
        int row = f >> 5, c4 = f & 31;
        float4 v = make_float4(0.f, 0.f, 0.f, 0.f);
        if (i0 + row < nrows)
            v = *(const float4*)&X[(size_t)(i0 + row) * 128 + c4 * 4];
        *(float4*)&xs[row][c4 * 4] = v;
    }
    __syncthreads();

    int ty = tid >> 5, tx = tid & 31;      // ty: row group (8 rows), tx: col/4
    float accl[8][4] = {{0}}, accr[8][4] = {{0}};

    for (int k = 0; k < 128; k += 4) {
        float4 a[8];
        #pragma unroll
        for (int r = 0; r < 8; ++r)
            a[r] = *(const float4*)&xs[ty * 8 + r][k];
        #pragma unroll
        for (int kk = 0; kk < 4; ++kk) {
            float4 wl = *(const float4*)&Wl[(size_t)(k + kk) * 128 + tx * 4];
            float4 wr = *(const float4*)&Wr[(size_t)(k + kk) * 128 + tx * 4];
            #pragma unroll
            for (int r = 0; r < 8; ++r) {
                float av = ((const float*)&a[r])[kk];
                accl[r][0] += av * wl.x; accl[r][1] += av * wl.y;
                accl[r][2] += av * wl.z; accl[r][3] += av * wl.w;
                accr[r][0] += av * wr.x; accr[r][1] += av * wr.y;
                accr[r][2] += av * wr.z; accr[r][3] += av * wr.w;
            }
        }
    }

    float4 vbl = *(const float4*)&bl[tx * 4];
    float4 vbr = *(const float4*)&br[tx * 4];
    #pragma unroll
    for (int r = 0; r < 8; ++r) {
        int row = i0 + ty * 8 + r;
        if (row >= nrows) continue;
        float4 ol = make_float4(accl[r][0] + vbl.x, accl[r][1] + vbl.y,
                                accl[r][2] + vbl.z, accl[r][3] + vbl.w);
        float4 orr = make_float4(accr[r][0] + vbr.x, accr[r][1] + vbr.y,
                                 accr[r][2] + vbr.z, accr[r][3] + vbr.w);
        *(float4*)&xl[(size_t)row * 128 + tx * 4] = ol;
        *(float4*)&xr[(size_t)row * 128 + tx * 4] = orr;
    }
}

// ---------------------------------------------------------------------------
// Fused GATv2 aggregation: one wave per node, online softmax over in-edges.
// lane l holds channels {l (head0), 64+l (head1)}.
// ---------------------------------------------------------------------------
__global__ __launch_bounds__(256) void gat_aggregate(
        const float* __restrict__ xl, const float* __restrict__ xr,
        const int* __restrict__ rowptr, const int* __restrict__ esrc,
        const float* __restrict__ att, const float* __restrict__ bias,
        float* __restrict__ hout, int n, int do_relu) {
    int node = (int)((blockIdx.x * blockDim.x + threadIdx.x) >> 6);
    int lane = threadIdx.x & 63;
    if (node >= n) return;

    float xr0  = xr[(size_t)node * 128 + lane];
    float xr1  = xr[(size_t)node * 128 + 64 + lane];
    float att0 = att[lane];
    float att1 = att[64 + lane];

    float m0 = -INFINITY, m1 = -INFINITY;
    float s0 = 0.f, s1 = 0.f, acc0 = 0.f, acc1 = 0.f;

    int pbeg = rowptr[node], pend = rowptr[node + 1];
    for (int p = pbeg; p < pend; ++p) {
        int s = esrc[p];
        float a0 = xl[(size_t)s * 128 + lane];
        float a1 = xl[(size_t)s * 128 + 64 + lane];
        float v0 = a0 + xr0, v1 = a1 + xr1;
        float l0 = v0 > 0.f ? v0 : NEG * v0;
        float l1 = v1 > 0.f ? v1 : NEG * v1;
        float t0 = l0 * att0, t1 = l1 * att1;
        #pragma unroll
        for (int off = 32; off > 0; off >>= 1) {
            t0 += __shfl_xor(t0, off, 64);
            t1 += __shfl_xor(t1, off, 64);
        }
        float nm0 = fmaxf(m0, t0), nm1 = fmaxf(m1, t1);
        float sc0 = __expf(m0 - nm0), sc1 = __expf(m1 - nm1);
        float p0  = __expf(t0 - nm0), p1  = __expf(t1 - nm1);
        s0 = s0 * sc0 + p0;          s1 = s1 * sc1 + p1;
        acc0 = acc0 * sc0 + p0 * a0; acc1 = acc1 * sc1 + p1 * a1;
        m0 = nm0; m1 = nm1;
    }

    float o0 = acc0 / s0 + bias[lane];
    float o1 = acc1 / s1 + bias[64 + lane];
    if (do_relu) { o0 = fmaxf(o0, 0.f); o1 = fmaxf(o1, 0.f); }
    hout[(size_t)node * 128 + lane]      = o0;
    hout[(size_t)node * 128 + 64 + lane] = o1;
}

// ---------------------------------------------------------------------------
// Output linear: out = h @ Wout + bout.  Wout:[128,4] row-major.
// ---------------------------------------------------------------------------
__global__ __launch_bounds__(256) void out_linear(
        const float* __restrict__ h, const float* __restrict__ Wout,
        const float* __restrict__ bout, float* __restrict__ out, int n) {
    int node = (int)((blockIdx.x * blockDim.x + threadIdx.x) >> 6);
    int lane = threadIdx.x & 63;
    if (node >= n) return;
    float h0 = h[(size_t)node * 128 + lane];
    float h1 = h[(size_t)node * 128 + 64 + lane];
    float4 w0 = *(const float4*)&Wout[lane * 4];
    float4 w1 = *(const float4*)&Wout[(64 + lane) * 4];
    float p0 = h0 * w0.x + h1 * w1.x;
    float p1 = h0 * w0.y + h1 * w1.y;
    float p2 = h0 * w0.z + h1 * w1.z;
    float p3 = h0 * w0.w + h1 * w1.w;
    #pragma unroll
    for (int off = 32; off > 0; off >>= 1) {
        p0 += __shfl_xor(p0, off, 64);
        p1 += __shfl_xor(p1, off, 64);
        p2 += __shfl_xor(p2, off, 64);
        p3 += __shfl_xor(p3, off, 64);
    }
    if (lane == 0) {
        float4 o = make_float4(p0 + bout[0], p1 + bout[1],
                               p2 + bout[2], p3 + bout[3]);
        *(float4*)&out[(size_t)node * 4] = o;
    }
}

// ---------------------------------------------------------------------------
extern "C" void kernel_launch(void* const* d_in, const int* in_sizes, int n_in,
                              void* d_out, int out_size, void* d_ws,
                              size_t ws_size, hipStream_t stream) {
    const float* x    = (const float*)d_in[0];
    const int*   ei   = (const int*)  d_in[1];
    const float* W1l  = (const float*)d_in[2];
    const float* b1l  = (const float*)d_in[3];
    const float* W1r  = (const float*)d_in[4];
    const float* b1r  = (const float*)d_in[5];
    const float* att1 = (const float*)d_in[6];
    const float* bias1= (const float*)d_in[7];
    const float* W2l  = (const float*)d_in[8];
    const float* b2l  = (const float*)d_in[9];
    const float* W2r  = (const float*)d_in[10];
    const float* b2r  = (const float*)d_in[11];
    const float* att2 = (const float*)d_in[12];
    const float* bias2= (const float*)d_in[13];
    const float* W3l  = (const float*)d_in[14];
    const float* b3l  = (const float*)d_in[15];
    const float* W3r  = (const float*)d_in[16];
    const float* b3r  = (const float*)d_in[17];
    const float* att3 = (const float*)d_in[18];
    const float* bias3= (const float*)d_in[19];
    const float* Wout = (const float*)d_in[20];
    const float* bout = (const float*)d_in[21];

    int N    = in_sizes[0] / DIN;
    int E    = in_sizes[1] / 2;
    int Etot = E + N;

    float* h      = (float*)d_ws;
    float* xl     = h  + (size_t)N * HC;
    float* xr     = xl + (size_t)N * HC;
    int*   esrc   = (int*)(xr + (size_t)N * HC);
    int*   rowptr = esrc + Etot;
    int*   cursor = rowptr + (N + 1);
    int*   counts = cursor + N;

    // --- CSR build (same every call; rebuilt to keep launch deterministic) ---
    hipMemsetAsync(counts, 0, (size_t)N * sizeof(int), stream);
    hist_kernel<<<(Etot + 255) / 256, 256, 0, stream>>>(ei, E, N, counts);
    scan_kernel<<<1, 1024, 0, stream>>>(counts, rowptr, cursor, N);
    scatter_kernel<<<(Etot + 255) / 256, 256, 0, stream>>>(ei, E, N, cursor, esrc);

    int gemm_grid = (N + 63) / 64;
    int agg_grid  = (N + 3) / 4;

    // --- layer 1 (input = x) ---
    gemm_dual<<<gemm_grid, 256, 0, stream>>>(x, W1l, b1l, W1r, b1r, xl, xr, N);
    gat_aggregate<<<agg_grid, 256, 0, stream>>>(xl, xr, rowptr, esrc, att1, bias1, h, N, 1);
    // --- layer 2 ---
    gemm_dual<<<gemm_grid, 256, 0, stream>>>(h, W2l, b2l, W2r, b2r, xl, xr, N);
    gat_aggregate<<<agg_grid, 256, 0, stream>>>(xl, xr, rowptr, esrc, att2, bias2, h, N, 1);
    // --- layer 3 ---
    gemm_dual<<<gemm_grid, 256, 0, stream>>>(h, W3l, b3l, W3r, b3r, xl, xr, N);
    gat_aggregate<<<agg_grid, 256, 0, stream>>>(xl, xr, rowptr, esrc, att3, bias3, h, N, 1);
    // --- output projection ---
    out_linear<<<(N + 3) / 4, 256, 0, stream>>>(h, Wout, bout, (float*)d_out, N);
}

// Round 2
// 529.726 us; speedup vs baseline: 1.3620x; 1.3620x over previous
//
#include <hip/hip_runtime.h>
#include <math.h>

#define DIN  128
#define HC   128
#define CCH  64
#define NEG  0.2f

// ---------------------------------------------------------------------------
// CSR build
// ---------------------------------------------------------------------------
__global__ void hist_kernel(const int* __restrict__ ei, int E, int N,
                            int* __restrict__ counts) {
    int i = blockIdx.x * blockDim.x + threadIdx.x;
    int Etot = E + N;
    if (i >= Etot) return;
    int dst = (i < E) ? ei[E + i] : (i - E);
    if (dst < 0 || dst >= N) return;
    atomicAdd(&counts[dst], 1);
}

__global__ void scan_kernel(const int* __restrict__ counts,
                            int* __restrict__ rowptr,
                            int* __restrict__ cursor, int n) {
    __shared__ int wsum[16];
    int tid  = threadIdx.x;          // 1024 threads
    int lane = tid & 63, wid = tid >> 6;
    int running = 0;
    for (int base = 0; base < n; base += 1024) {
        int i = base + tid;
        int v = (i < n) ? counts[i] : 0;
        int x = v;
        #pragma unroll
        for (int off = 1; off < 64; off <<= 1) {
            int y = __shfl_up(x, off, 64);
            if (lane >= off) x += y;
        }
        if (lane == 63) wsum[wid] = x;
        __syncthreads();
        if (tid < 16) {
            int w = wsum[tid];
            #pragma unroll
            for (int off = 1; off < 16; off <<= 1) {
                int y = __shfl_up(w, off, 64);
                if (tid >= off) w += y;
            }
            wsum[tid] = w;
        }
        __syncthreads();
        int excl = running + (wid ? wsum[wid - 1] : 0) + (x - v);
        if (i < n) { rowptr[i] = excl; cursor[i] = excl; }
        running += wsum[15];
        __syncthreads();
    }
    if (tid == 0) rowptr[n] = running;
}

__global__ void scatter_kernel(const int* __restrict__ ei, int E, int N,
                               int* __restrict__ cursor,
                               int* __restrict__ esrc) {
    int i = blockIdx.x * blockDim.x + threadIdx.x;
    int Etot = E + N;
    if (i >= Etot) return;
    int src = (i < E) ? ei[i]     : (i - E);
    int dst = (i < E) ? ei[E + i] : (i - E);
    if (dst < 0 || dst >= N || src < 0 || src >= N) return;
    int pos = atomicAdd(&cursor[dst], 1);
    esrc[pos] = src;
}

// ---------------------------------------------------------------------------
// Dual GEMM: xl = X@Wl + bl, xr = X@Wr + br.  X:[n,128], W:[128,128] row-major
// ---------------------------------------------------------------------------
__global__ __launch_bounds__(256) void gemm_dual(
        const float* __restrict__ X,
        const float* __restrict__ Wl, const float* __restrict__ bl,
        const float* __restrict__ Wr, const float* __restrict__ br,
        float* __restrict__ xl, float* __restrict__ xr, int nrows) {
    __shared__ float xs[64][128];
    int tid = threadIdx.x;
    int i0  = blockIdx.x * 64;

    #pragma unroll
    for (int it = 0; it < 8; ++it) {
        int f   = it * 256 + tid;
        int row = f >> 5, c4 = f & 31;
        float4 v = make_float4(0.f, 0.f, 0.f, 0.f);
        if (i0 + row < nrows)
            v = *(const float4*)&X[(size_t)(i0 + row) * 128 + c4 * 4];
        *(float4*)&xs[row][c4 * 4] = v;
    }
    __syncthreads();

    int ty = tid >> 5, tx = tid & 31;
    float accl[8][4] = {{0}}, accr[8][4] = {{0}};

    for (int k = 0; k < 128; k += 4) {
        float4 a[8];
        #pragma unroll
        for (int r = 0; r < 8; ++r)
            a[r] = *(const float4*)&xs[ty * 8 + r][k];
        #pragma unroll
        for (int kk = 0; kk < 4; ++kk) {
            float4 wl = *(const float4*)&Wl[(size_t)(k + kk) * 128 + tx * 4];
            float4 wr = *(const float4*)&Wr[(size_t)(k + kk) * 128 + tx * 4];
            #pragma unroll
            for (int r = 0; r < 8; ++r) {
                float av = ((const float*)&a[r])[kk];
                accl[r][0] += av * wl.x; accl[r][1] += av * wl.y;
                accl[r][2] += av * wl.z; accl[r][3] += av * wl.w;
                accr[r][0] += av * wr.x; accr[r][1] += av * wr.y;
                accr[r][2] += av * wr.z; accr[r][3] += av * wr.w;
            }
        }
    }

    float4 vbl = *(const float4*)&bl[tx * 4];
    float4 vbr = *(const float4*)&br[tx * 4];
    #pragma unroll
    for (int r = 0; r < 8; ++r) {
        int row = i0 + ty * 8 + r;
        if (row >= nrows) continue;
        float4 ol = make_float4(accl[r][0] + vbl.x, accl[r][1] + vbl.y,
                                accl[r][2] + vbl.z, accl[r][3] + vbl.w);
        float4 orr = make_float4(accr[r][0] + vbr.x, accr[r][1] + vbr.y,
                                 accr[r][2] + vbr.z, accr[r][3] + vbr.w);
        *(float4*)&xl[(size_t)row * 128 + tx * 4] = ol;
        *(float4*)&xr[(size_t)row * 128 + tx * 4] = orr;
    }
}

// ---------------------------------------------------------------------------
// Fused GATv2 aggregation, 4 edges in flight per wave.
// Wave = 1 node. Lanes: 4 groups x 16. Group g processes edges pbeg+g, +4...
// Lane (g, gl) holds channels [4*gl..4*gl+3] (head0) and [64+4*gl..] (head1).
// Each group keeps an independent online-softmax state; flash-merge at end.
// ---------------------------------------------------------------------------
__device__ __forceinline__ float lrelu(float v) {
    return v > 0.f ? v : NEG * v;
}

__global__ __launch_bounds__(256) void gat_aggregate(
        const float* __restrict__ xl, const float* __restrict__ xr,
        const int* __restrict__ rowptr, const int* __restrict__ esrc,
        const float* __restrict__ att, const float* __restrict__ bias,
        float* __restrict__ hout, int n, int do_relu) {
    int node = (int)((blockIdx.x * blockDim.x + threadIdx.x) >> 6);
    int lane = threadIdx.x & 63;
    if (node >= n) return;
    int g  = lane >> 4;
    int gl = lane & 15;
    int c0 = gl * 4;

    const float* xrp = &xr[(size_t)node * 128];
    float4 xr0 = *(const float4*)&xrp[c0];
    float4 xr1 = *(const float4*)&xrp[64 + c0];
    float4 at0 = *(const float4*)&att[c0];
    float4 at1 = *(const float4*)&att[64 + c0];

    float m0 = -1e30f, m1 = -1e30f, s0 = 0.f, s1 = 0.f;
    float4 acc0 = make_float4(0.f, 0.f, 0.f, 0.f);
    float4 acc1 = make_float4(0.f, 0.f, 0.f, 0.f);

    int pbeg = rowptr[node], pend = rowptr[node + 1];
    for (int p = pbeg + g; p < pend; p += 4) {
        int s = esrc[p];
        const float* xlp = &xl[(size_t)s * 128];
        float4 a0 = *(const float4*)&xlp[c0];
        float4 a1 = *(const float4*)&xlp[64 + c0];

        float t0 = lrelu(a0.x + xr0.x) * at0.x + lrelu(a0.y + xr0.y) * at0.y
                 + lrelu(a0.z + xr0.z) * at0.z + lrelu(a0.w + xr0.w) * at0.w;
        float t1 = lrelu(a1.x + xr1.x) * at1.x + lrelu(a1.y + xr1.y) * at1.y
                 + lrelu(a1.z + xr1.z) * at1.z + lrelu(a1.w + xr1.w) * at1.w;
        #pragma unroll
        for (int off = 1; off < 16; off <<= 1) {
            t0 += __shfl_xor(t0, off, 64);
            t1 += __shfl_xor(t1, off, 64);
        }

        float nm0 = fmaxf(m0, t0), nm1 = fmaxf(m1, t1);
        float sc0 = __expf(m0 - nm0), sc1 = __expf(m1 - nm1);
        float p0  = __expf(t0 - nm0), p1  = __expf(t1 - nm1);
        s0 = s0 * sc0 + p0;  s1 = s1 * sc1 + p1;
        acc0.x = acc0.x * sc0 + p0 * a0.x;  acc0.y = acc0.y * sc0 + p0 * a0.y;
        acc0.z = acc0.z * sc0 + p0 * a0.z;  acc0.w = acc0.w * sc0 + p0 * a0.w;
        acc1.x = acc1.x * sc1 + p1 * a1.x;  acc1.y = acc1.y * sc1 + p1 * a1.y;
        acc1.z = acc1.z * sc1 + p1 * a1.z;  acc1.w = acc1.w * sc1 + p1 * a1.w;
        m0 = nm0; m1 = nm1;
    }

    // flash-merge the 4 group states (xor 16 then 32)
    #pragma unroll
    for (int off = 16; off <= 32; off <<= 1) {
        float om0 = __shfl_xor(m0, off, 64), om1 = __shfl_xor(m1, off, 64);
        float os0 = __shfl_xor(s0, off, 64), os1 = __shfl_xor(s1, off, 64);
        float4 oa0, oa1;
        oa0.x = __shfl_xor(acc0.x, off, 64); oa0.y = __shfl_xor(acc0.y, off, 64);
        oa0.z = __shfl_xor(acc0.z, off, 64); oa0.w = __shfl_xor(acc0.w, off, 64);
        oa1.x = __shfl_xor(acc1.x, off, 64); oa1.y = __shfl_xor(acc1.y, off, 64);
        oa1.z = __shfl_xor(acc1.z, off, 64); oa1.w = __shfl_xor(acc1.w, off, 64);

        float nm0 = fmaxf(m0, om0), nm1 = fmaxf(m1, om1);
        float sa0 = __expf(m0 - nm0),  sb0 = __expf(om0 - nm0);
        float sa1 = __expf(m1 - nm1),  sb1 = __expf(om1 - nm1);
        s0 = s0 * sa0 + os0 * sb0;  s1 = s1 * sa1 + os1 * sb1;
        acc0.x = acc0.x * sa0 + oa0.x * sb0;  acc0.y = acc0.y * sa0 + oa0.y * sb0;
        acc0.z = acc0.z * sa0 + oa0.z * sb0;  acc0.w = acc0.w * sa0 + oa0.w * sb0;
        acc1.x = acc1.x * sa1 + oa1.x * sb1;  acc1.y = acc1.y * sa1 + oa1.y * sb1;
        acc1.z = acc1.z * sa1 + oa1.z * sb1;  acc1.w = acc1.w * sa1 + oa1.w * sb1;
        m0 = nm0; m1 = nm1;
    }

    float inv0 = 1.f / s0, inv1 = 1.f / s1;
    if (g == 0) {
        float4 vb = *(const float4*)&bias[c0];
        float4 o = make_float4(acc0.x * inv0 + vb.x, acc0.y * inv0 + vb.y,
                               acc0.z * inv0 + vb.z, acc0.w * inv0 + vb.w);
        if (do_relu) {
            o.x = fmaxf(o.x, 0.f); o.y = fmaxf(o.y, 0.f);
            o.z = fmaxf(o.z, 0.f); o.w = fmaxf(o.w, 0.f);
        }
        *(float4*)&hout[(size_t)node * 128 + c0] = o;
    } else if (g == 1) {
        float4 vb = *(const float4*)&bias[64 + c0];
        float4 o = make_float4(acc1.x * inv1 + vb.x, acc1.y * inv1 + vb.y,
                               acc1.z * inv1 + vb.z, acc1.w * inv1 + vb.w);
        if (do_relu) {
            o.x = fmaxf(o.x, 0.f); o.y = fmaxf(o.y, 0.f);
            o.z = fmaxf(o.z, 0.f); o.w = fmaxf(o.w, 0.f);
        }
        *(float4*)&hout[(size_t)node * 128 + 64 + c0] = o;
    }
}

// ---------------------------------------------------------------------------
// Output linear: out = h @ Wout + bout.  Wout:[128,4] row-major.
// ---------------------------------------------------------------------------
__global__ __launch_bounds__(256) void out_linear(
        const float* __restrict__ h, const float* __restrict__ Wout,
        const float* __restrict__ bout, float* __restrict__ out, int n) {
    int node = (int)((blockIdx.x * blockDim.x + threadIdx.x) >> 6);
    int lane = threadIdx.x & 63;
    if (node >= n) return;
    float h0 = h[(size_t)node * 128 + lane];
    float h1 = h[(size_t)node * 128 + 64 + lane];
    float4 w0 = *(const float4*)&Wout[lane * 4];
    float4 w1 = *(const float4*)&Wout[(64 + lane) * 4];
    float p0 = h0 * w0.x + h1 * w1.x;
    float p1 = h0 * w0.y + h1 * w1.y;
    float p2 = h0 * w0.z + h1 * w1.z;
    float p3 = h0 * w0.w + h1 * w1.w;
    #pragma unroll
    for (int off = 32; off > 0; off >>= 1) {
        p0 += __shfl_xor(p0, off, 64);
        p1 += __shfl_xor(p1, off, 64);
        p2 += __shfl_xor(p2, off, 64);
        p3 += __shfl_xor(p3, off, 64);
    }
    if (lane == 0) {
        float4 o = make_float4(p0 + bout[0], p1 + bout[1],
                               p2 + bout[2], p3 + bout[3]);
        *(float4*)&out[(size_t)node * 4] = o;
    }
}

// ---------------------------------------------------------------------------
extern "C" void kernel_launch(void* const* d_in, const int* in_sizes, int n_in,
                              void* d_out, int out_size, void* d_ws,
                              size_t ws_size, hipStream_t stream) {
    const float* x    = (const float*)d_in[0];
    const int*   ei   = (const int*)  d_in[1];
    const float* W1l  = (const float*)d_in[2];
    const float* b1l  = (const float*)d_in[3];
    const float* W1r  = (const float*)d_in[4];
    const float* b1r  = (const float*)d_in[5];
    const float* att1 = (const float*)d_in[6];
    const float* bias1= (const float*)d_in[7];
    const float* W2l  = (const float*)d_in[8];
    const float* b2l  = (const float*)d_in[9];
    const float* W2r  = (const float*)d_in[10];
    const float* b2r  = (const float*)d_in[11];
    const float* att2 = (const float*)d_in[12];
    const float* bias2= (const float*)d_in[13];
    const float* W3l  = (const float*)d_in[14];
    const float* b3l  = (const float*)d_in[15];
    const float* W3r  = (const float*)d_in[16];
    const float* b3r  = (const float*)d_in[17];
    const float* att3 = (const float*)d_in[18];
    const float* bias3= (const float*)d_in[19];
    const float* Wout = (const float*)d_in[20];
    const float* bout = (const float*)d_in[21];

    int N    = in_sizes[0] / DIN;
    int E    = in_sizes[1] / 2;
    int Etot = E + N;

    float* h      = (float*)d_ws;
    float* xl     = h  + (size_t)N * HC;
    float* xr     = xl + (size_t)N * HC;
    int*   esrc   = (int*)(xr + (size_t)N * HC);
    int*   rowptr = esrc + Etot;
    int*   cursor = rowptr + (N + 1);
    int*   counts = cursor + N;

    hipMemsetAsync(counts, 0, (size_t)N * sizeof(int), stream);
    hist_kernel<<<(Etot + 255) / 256, 256, 0, stream>>>(ei, E, N, counts);
    scan_kernel<<<1, 1024, 0, stream>>>(counts, rowptr, cursor, N);
    scatter_kernel<<<(Etot + 255) / 256, 256, 0, stream>>>(ei, E, N, cursor, esrc);

    int gemm_grid = (N + 63) / 64;
    int agg_grid  = (N + 3) / 4;

    gemm_dual<<<gemm_grid, 256, 0, stream>>>(x, W1l, b1l, W1r, b1r, xl, xr, N);
    gat_aggregate<<<agg_grid, 256, 0, stream>>>(xl, xr, rowptr, esrc, att1, bias1, h, N, 1);
    gemm_dual<<<gemm_grid, 256, 0, stream>>>(h, W2l, b2l, W2r, b2r, xl, xr, N);
    gat_aggregate<<<agg_grid, 256, 0, stream>>>(xl, xr, rowptr, esrc, att2, bias2, h, N, 1);
    gemm_dual<<<gemm_grid, 256, 0, stream>>>(h, W3l, b3l, W3r, b3r, xl, xr, N);
    gat_aggregate<<<agg_grid, 256, 0, stream>>>(xl, xr, rowptr, esrc, att3, bias3, h, N, 1);
    out_linear<<<(N + 3) / 4, 256, 0, stream>>>(h, Wout, bout, (float*)d_out, N);
}